// Round 5
// baseline (655.267 us; speedup 1.0000x reference)
//
#include <hip/hip_runtime.h>

typedef _Float16 f16;
typedef _Float16 f16x8 __attribute__((ext_vector_type(8)));
typedef float f32x4 __attribute__((ext_vector_type(4)));
typedef float f32x16 __attribute__((ext_vector_type(16)));

#define NB 32
#define NT 512
#define ND 256
#define NH 512
#define NK 8
#define M_REAL 16352   // NB*(NT-1)
#define M_PAD 16384
#define RDIM 768       // ND + NH
#define TILE_ELEMS 98304  // 96 ch * 128 rows * 8 f16 per tile

// output offsets (floats)
#define OFF_PI 0
#define OFF_S  256
#define OFF_H  1048832
#define OFF_Y  1179904
#define OFF_G1 1196288
#define OFF_G2 1327360
#define OFF_F  2373888
#define OFF_BW 2504960

// ws offsets (bytes)
#define WS_A    0            // f16 tiled [128][96][128][8] = 25165824 B
#define WS_B    25165824     // f16 tiled [32][96][128][8]  = 6291456 B
#define WS_BIAS 31457280     // f32 [4096]
#define WS_SQ   31473664     // f32 [16384][8][8] = 4194304 B
#define WS_NEED 35667968

#define CH_CONST 1887.3506062251f   // -0.5*512*(log(2pi)+log(1e-4))
#define CY_CONST 943.6753031126f    // -0.5*256*(...)
#define LOG2E 1.4426950408889634f
#define LN2 0.6931471805599453f

__device__ __forceinline__ float fexp2(float x) { return __builtin_amdgcn_exp2f(x); }
__device__ __forceinline__ float flog2(float x) { return __builtin_amdgcn_logf(x); }
__device__ __forceinline__ float ftanh(float x) {
    x = fminf(10.f, fmaxf(-10.f, x));
    float t = fexp2(x * 2.885390081777927f);  // 2*log2(e)
    return (t - 1.f) * __builtin_amdgcn_rcpf(t + 1.f);
}
__device__ __forceinline__ float lse8v(const float* z) {
    float M = fmaxf(fmaxf(fmaxf(z[0], z[1]), fmaxf(z[2], z[3])),
                    fmaxf(fmaxf(z[4], z[5]), fmaxf(z[6], z[7])));
    float s = 0.f;
#pragma unroll
    for (int j = 0; j < 8; ++j) s += fexp2((z[j] - M) * LOG2E);
    return M + LN2 * flog2(s);
}

// ---------------- conversion kernels (write GEMM-tiled layout) ----------------
// tiled index for (row m, col c): (m>>7)*98304 + (c>>3)*1024 + (m&127)*8 + (c&7)
__global__ void conv_a_kernel(const float* __restrict__ x, const float* __restrict__ h,
                              f16* __restrict__ A) {
    const int g = blockIdx.x * 256 + threadIdx.x;  // < 16384*96
    const int m = g / 96;
    const int ch = g - m * 96;
    f16x8 pk = (f16x8)(f16)0.f;
    if (m < M_REAL) {
        const int b = m / 511;
        const int t = m - b * 511;
        const int c0 = ch * 8;
        const float* src = (c0 < ND) ? x + (size_t)(b * NT + t + 1) * ND + c0
                                     : h + (size_t)(b * NT + t) * NH + (c0 - ND);
        const float4 u = ((const float4*)src)[0];
        const float4 v = ((const float4*)src)[1];
        pk[0] = (f16)u.x; pk[1] = (f16)u.y; pk[2] = (f16)u.z; pk[3] = (f16)u.w;
        pk[4] = (f16)v.x; pk[5] = (f16)v.y; pk[6] = (f16)v.z; pk[7] = (f16)v.w;
    }
    const size_t dst = (size_t)(m >> 7) * TILE_ELEMS + (size_t)ch * 1024 + (size_t)(m & 127) * 8;
    *(f16x8*)(A + dst) = pk;
}

__global__ void conv_b_kernel(const float* __restrict__ Wih, const float* __restrict__ Whh,
                              const float* __restrict__ bih, const float* __restrict__ bhh,
                              f16* __restrict__ Bm, float* __restrict__ biasc) {
    const int g = blockIdx.x * 256 + threadIdx.x;  // < 4096*96
    const int n = g / 96;
    const int ch = g - n * 96;
    const int c0 = ch * 8;
    const float* src = (c0 < ND) ? Wih + (size_t)n * ND + c0 : Whh + (size_t)n * NH + (c0 - ND);
    const float4 u = ((const float4*)src)[0];
    const float4 v = ((const float4*)src)[1];
    f16x8 pk;
    pk[0] = (f16)u.x; pk[1] = (f16)u.y; pk[2] = (f16)u.z; pk[3] = (f16)u.w;
    pk[4] = (f16)v.x; pk[5] = (f16)v.y; pk[6] = (f16)v.z; pk[7] = (f16)v.w;
    const size_t dst = (size_t)(n >> 7) * TILE_ELEMS + (size_t)ch * 1024 + (size_t)(n & 127) * 8;
    *(f16x8*)(Bm + dst) = pk;
    if (ch == 0) biasc[n] = bih[n] + bhh[n];
}

// ------- big GEMM (32x32x16 MFMA, double-buffered LDS) + tanh + sq epilogue ----
__global__ __launch_bounds__(256) void gemm_kernel(const f16* __restrict__ A,
                                                   const f16* __restrict__ Bm,
                                                   const float* __restrict__ biasc,
                                                   const float* __restrict__ sampled_h,
                                                   float* __restrict__ sq_part) {
    // double buffer: loads for iter k+1 issued before compute(k); the vmcnt(0)
    // drain at the next barrier then waits on loads that already had a full
    // compute phase in flight (latency-bound fix; issue-rate was not the wall)
    __shared__ __align__(16) f16 Ash[2][8 * 128 * 8];
    __shared__ __align__(16) f16 Bsh[2][8 * 128 * 8];
    const int tid = threadIdx.x;
    const int lane = tid & 63;
    const int wave = tid >> 6;
    const int wx = wave & 1, wy = wave >> 1;
    // XCD-aware swizzle: each XCD owns 16 contiguous m-panels (A stays in its L2)
    const int xcd = blockIdx.x & 7;
    const int slot = blockIdx.x >> 3;
    const int tm = xcd * 16 + (slot >> 5);
    const int tn = slot & 31;
    const int m0 = tm * 128, n0 = tn * 128;
    const int l31 = lane & 31, hk = lane >> 5;

    const size_t abase0 = (size_t)tm * TILE_ELEMS;
    const size_t bbase0 = (size_t)tn * TILE_ELEMS;

    f32x16 acc[2][2];
#pragma unroll
    for (int a = 0; a < 2; ++a)
#pragma unroll
        for (int b = 0; b < 2; ++b) acc[a][b] = (f32x16)0.f;

    // stage(kk -> buf): 8 contiguous 1KB global_load_lds per wave-quarter
#define STAGE(KK, BUF)                                                                   \
    {                                                                                    \
        const size_t ab = abase0 + (size_t)(KK)*128;                                     \
        const size_t bb = bbase0 + (size_t)(KK)*128;                                     \
        _Pragma("unroll") for (int inst = 0; inst < 4; ++inst) {                         \
            const int fb = inst * 256 + wave * 64; /* wave-uniform */                    \
            const f16* ga = A + ab + (size_t)(fb + lane) * 8;                            \
            const f16* gb = Bm + bb + (size_t)(fb + lane) * 8;                           \
            __builtin_amdgcn_global_load_lds(                                            \
                (const __attribute__((address_space(1))) void*)ga,                       \
                (__attribute__((address_space(3))) void*)&Ash[BUF][fb * 8], 16, 0, 0);   \
            __builtin_amdgcn_global_load_lds(                                            \
                (const __attribute__((address_space(1))) void*)gb,                       \
                (__attribute__((address_space(3))) void*)&Bsh[BUF][fb * 8], 16, 0, 0);   \
        }                                                                                \
    }

    STAGE(0, 0);
    int buf = 0;
    for (int kk = 0; kk < RDIM; kk += 64) {
        __syncthreads();  // drains vmcnt(0): buf's loads done; prev compute's ds_reads done
        if (kk + 64 < RDIM) STAGE(kk + 64, buf ^ 1);
        // A-frag for 32x32x16: lane holds A[m=lane&31][k=(lane>>5)*8+j]
#pragma unroll
        for (int kc = 0; kc < 4; ++kc) {
            const int ch = kc * 2 + hk;
            f16x8 af[2], bfr[2];
#pragma unroll
            for (int mi = 0; mi < 2; ++mi)
                af[mi] = *(const f16x8*)&Ash[buf][(ch * 128 + wy * 64 + mi * 32 + l31) * 8];
#pragma unroll
            for (int ni = 0; ni < 2; ++ni)
                bfr[ni] = *(const f16x8*)&Bsh[buf][(ch * 128 + wx * 64 + ni * 32 + l31) * 8];
#pragma unroll
            for (int mi = 0; mi < 2; ++mi)
#pragma unroll
                for (int ni = 0; ni < 2; ++ni)
                    acc[mi][ni] = __builtin_amdgcn_mfma_f32_32x32x16_f16(af[mi], bfr[ni],
                                                                         acc[mi][ni], 0, 0, 0);
        }
        buf ^= 1;
    }
#undef STAGE

    // epilogue: C layout col=lane&31, row=(reg&3)+8*(reg>>2)+4*(lane>>5)
    const int nbase = n0 + wx * 64;
    const int k0 = n0 >> 9;
    const int slot2 = (nbase & 511) >> 6;  // 64-col slot within this k-group
    const float bias0 = biasc[nbase + l31];
    const float bias1 = biasc[nbase + 32 + l31];
#pragma unroll
    for (int mi = 0; mi < 2; ++mi) {
#pragma unroll
        for (int r = 0; r < 16; ++r) {
            const int mg = m0 + wy * 64 + mi * 32 + (r & 3) + 8 * (r >> 2) + 4 * hk;
            if (mg < M_REAL) {
                const int bb = mg / 511;
                const int tt = mg - bb * 511;
                const float* tgt = sampled_h + (size_t)((bb << 9) + tt + 1) * NH;
                float rs;
                {
                    const float v0 = ftanh(acc[mi][0][r] + bias0);
                    const float d0 = tgt[(nbase + l31) & 511] - v0;
                    const float v1 = ftanh(acc[mi][1][r] + bias1);
                    const float d1 = tgt[(nbase + 32 + l31) & 511] - v1;
                    rs = d0 * d0 + d1 * d1;
                }
                // reduce 32 lanes of this half (rows identical within half)
                rs += __shfl_xor(rs, 1, 64);
                rs += __shfl_xor(rs, 2, 64);
                rs += __shfl_xor(rs, 4, 64);
                rs += __shfl_xor(rs, 8, 64);
                rs += __shfl_xor(rs, 16, 64);
                if (l31 == 0) sq_part[(size_t)(mg * 8 + k0) * 8 + slot2] = rs;
            }
        }
    }
}

__global__ void finalize_h_kernel(const float* __restrict__ sq_part, float* __restrict__ Ph) {
    const int g = blockIdx.x * 256 + threadIdx.x;  // < 131072 = B*T*K
    const int b = g >> 12;
    const int t = (g >> 3) & 511;
    const int k = g & 7;
    float val;
    if (t == 0) {
        val = CH_CONST;
    } else {
        const int m = b * 511 + (t - 1);
        const float4* p = (const float4*)&sq_part[(size_t)(m * 8 + k) * 8];
        const float4 a = p[0], c = p[1];
        const float s = a.x + a.y + a.z + a.w + c.x + c.y + c.z + c.w;
        val = CH_CONST - 5000.f * s;  // 0.5/VAR = 5000
    }
    Ph[g] = val;
}

// ---------------- trans = tanh(h_prev @ Wt^T + bt), column log-softmax ----------------
__global__ __launch_bounds__(256) void trans_kernel(const float* __restrict__ h,
                                                    const float* __restrict__ Wt,
                                                    const float* __restrict__ btv,
                                                    float* __restrict__ Ps) {
    __shared__ float hsh[32][512];
    const int lane = threadIdx.x & 63;
    const int wave = threadIdx.x >> 6;
    const int mbase = blockIdx.x * 32 + wave * 8;  // 511 blocks * 32 rows = 16352
#pragma unroll
    for (int r = 0; r < 8; ++r) {
        const int m = mbase + r;
        const int b = m / 511, t = m - b * 511;
        const float4* src = (const float4*)(h + (size_t)(b * NT + t) * NH);
        ((float4*)hsh[wave * 8 + r])[lane] = src[lane];
        ((float4*)hsh[wave * 8 + r])[lane + 64] = src[lane + 64];
    }
    __syncthreads();
    const int c = lane;  // output index = i*8 + j
    float acc[8];
#pragma unroll
    for (int r = 0; r < 8; ++r) acc[r] = btv[c];
    const float4* w4 = (const float4*)(Wt + (size_t)c * NH);
    for (int hh = 0; hh < 128; ++hh) {
        const float4 w = w4[hh];
#pragma unroll
        for (int r = 0; r < 8; ++r) {
            const float4 hv = ((const float4*)hsh[wave * 8 + r])[hh];
            acc[r] += w.x * hv.x + w.y * hv.y + w.z * hv.z + w.w * hv.w;
        }
    }
#pragma unroll
    for (int r = 0; r < 8; ++r) {
        const float tr = ftanh(acc[r]);
        float M = tr;
        M = fmaxf(M, __shfl_xor(M, 8, 64));
        M = fmaxf(M, __shfl_xor(M, 16, 64));
        M = fmaxf(M, __shfl_xor(M, 32, 64));
        float s = fexp2((tr - M) * LOG2E);
        s += __shfl_xor(s, 8, 64);
        s += __shfl_xor(s, 16, 64);
        s += __shfl_xor(s, 32, 64);
        const float lse = M + LN2 * flog2(s);
        const int m = mbase + r;
        const int b = m / 511, t = m - b * 511;
        Ps[(size_t)(b * NT + t + 1) * 64 + c] = tr - lse;
    }
}

__global__ void s0_kernel(float* __restrict__ out) {
    const int g = blockIdx.x * 256 + threadIdx.x;  // < 2048
    const int b = g >> 6, c = g & 63;
    out[OFF_S + (size_t)b * NT * 64 + c] = ((c >> 3) == (c & 7)) ? 1.f : 0.f;
}

// ---------------- emission MLP + gaussian lp: phase-split, ~4 barriers/block ----
__global__ __launch_bounds__(256) void emission_kernel(
    const float* __restrict__ h, const float* __restrict__ y, const float* __restrict__ W1,
    const float* __restrict__ b1, const float* __restrict__ W2, const float* __restrict__ b2,
    const float* __restrict__ W3, const float* __restrict__ b3, float* __restrict__ Py) {
    __shared__ float ssh[16][512];   // 16 positions of h
    __shared__ float W2sh[64 * 33];  // padded stride 33
    __shared__ float h1sh[16][32];
    __shared__ float h2sh[16][64];
    __shared__ float red[16][4];
    const int tid = threadIdx.x;
    const int wv = tid >> 6;
    const int o = tid >> 3, seg = tid & 7;
    const int p0 = blockIdx.x * 16;
    // weights in registers — static indices only (dynamic reg idx = scratch spill)
    float4 w1r[16], w3r[16];
    {
        const float4* w1p = (const float4*)(W1 + (size_t)o * NH + seg * 64);
#pragma unroll
        for (int j = 0; j < 16; ++j) w1r[j] = w1p[(j + seg * 2) & 15];  // staggered load
        const float4* w3p = (const float4*)(W3 + (size_t)tid * 64);
#pragma unroll
        for (int j = 0; j < 16; ++j) w3r[j] = w3p[j];
    }
    if (tid < 64) {
        for (int j = 0; j < 32; ++j) W2sh[tid * 33 + j] = W2[tid * 32 + j];
    }
    float yv[16];
#pragma unroll
    for (int pp = 0; pp < 16; ++pp) yv[pp] = y[(size_t)(p0 + pp) * ND + tid];
    const float b1r = b1[o];
    const float b2r = b2[tid & 63];
    const float b3r = b3[tid];
    // phase 0: stage all 16 positions of h
#pragma unroll
    for (int pp = 0; pp < 16; ++pp) {
        const float2 hv = ((const float2*)(h + (size_t)(p0 + pp) * NH))[tid];
        ssh[pp][tid * 2] = hv.x;
        ssh[pp][tid * 2 + 1] = hv.y;
    }
    __syncthreads();
    // phase 1: layer1 for all positions; thread (o,seg) covers W1[o, seg*64..+63]
#pragma unroll
    for (int pp = 0; pp < 16; ++pp) {
        const float4* s4 = (const float4*)&ssh[pp][seg * 64];
        float p = 0.f;
#pragma unroll
        for (int it = 0; it < 16; ++it) {
            const float4 sv = s4[(it + seg * 2) & 15];  // dynamic LDS idx: ok
            const float4 w = w1r[it];                   // static reg idx
            p += w.x * sv.x + w.y * sv.y + w.z * sv.z + w.w * sv.w;
        }
        p += __shfl_xor(p, 1, 64);
        p += __shfl_xor(p, 2, 64);
        p += __shfl_xor(p, 4, 64);
        if (seg == 0) h1sh[pp][o] = fmaxf(p + b1r, 0.f);
    }
    __syncthreads();
    // phase 2: layer2; thread -> out o2=tid&63, positions wv*4..wv*4+3
    {
        const int o2 = tid & 63;
#pragma unroll
        for (int it = 0; it < 4; ++it) {
            const int pp = wv * 4 + it;
            float s = b2r;
#pragma unroll
            for (int j = 0; j < 32; ++j) s += W2sh[o2 * 33 + j] * h1sh[pp][j];
            h2sh[pp][o2] = fmaxf(s, 0.f);
        }
    }
    __syncthreads();
    // phase 3: layer3 + gaussian lp; thread owns dim d=tid
#pragma unroll
    for (int pp = 0; pp < 16; ++pp) {
        float s = b3r;
        const float4* h24 = (const float4*)h2sh[pp];
#pragma unroll
        for (int j = 0; j < 16; ++j) {
            const float4 w = w3r[j], hb = h24[j];
            s += w.x * hb.x + w.y * hb.y + w.z * hb.z + w.w * hb.w;
        }
        const float d = yv[pp] - s;
        float sq = d * d;
#pragma unroll
        for (int off = 32; off > 0; off >>= 1) sq += __shfl_xor(sq, off, 64);
        if ((tid & 63) == 0) red[pp][wv] = sq;
    }
    __syncthreads();
    if (tid < 16) {
        Py[p0 + tid] = CY_CONST - 5000.f * (red[tid][0] + red[tid][1] + red[tid][2] + red[tid][3]);
    }
}

__global__ void pinit_kernel(const float* __restrict__ initials, float* __restrict__ out) {
    const int tid = threadIdx.x;  // 256
    float z[8];
#pragma unroll
    for (int j = 0; j < 8; ++j) z[j] = initials[j];
    const float l = lse8v(z);
    out[OFF_PI + tid] = z[tid & 7] - l;
}

// ---------------- forward / backward scans: shfl-only, no barriers ----------------
__global__ __launch_bounds__(256) void scan_kernel(const float* __restrict__ initials,
                                                   float* __restrict__ out) {
    const float* Ps = out + OFF_S;
    const float* Ph = out + OFF_H;
    const float* Py = out + OFF_Y;
    const int lane = threadIdx.x & 63;
    const int wave = threadIdx.x >> 6;
    const int b = wave * 8 + (lane >> 3);
    const int i = lane & 7;
    const int lbase = lane & ~7;

    if (blockIdx.x == 0) {
        float z0[8];
#pragma unroll
        for (int j = 0; j < 8; ++j) z0[j] = initials[j];
        const float linit = lse8v(z0);
        float* Fw = out + OFF_F;
        float a = (z0[i] - linit) + CH_CONST + Py[b * NT];
        Fw[(size_t)(b * NT) * 8 + i] = a;
        size_t base = (size_t)(b * NT + 1) * 64 + i * 8;
        float4 sA = *(const float4*)&Ps[base];
        float4 sB = *(const float4*)&Ps[base + 4];
        float eh = Ph[(size_t)(b * NT + 1) * 8 + i];
        float ey = Py[b * NT + 1];
        for (int t = 1; t < NT; ++t) {
            const float4 cA = sA, cB = sB;
            const float ce = eh + ey;
            if (t + 1 < NT) {
                base = (size_t)(b * NT + t + 1) * 64 + i * 8;
                sA = *(const float4*)&Ps[base];
                sB = *(const float4*)&Ps[base + 4];
                eh = Ph[(size_t)(b * NT + t + 1) * 8 + i];
                ey = Py[b * NT + t + 1];
            }
            float z[8];
            z[0] = __shfl(a, lbase + 0, 64) + cA.x;
            z[1] = __shfl(a, lbase + 1, 64) + cA.y;
            z[2] = __shfl(a, lbase + 2, 64) + cA.z;
            z[3] = __shfl(a, lbase + 3, 64) + cA.w;
            z[4] = __shfl(a, lbase + 4, 64) + cB.x;
            z[5] = __shfl(a, lbase + 5, 64) + cB.y;
            z[6] = __shfl(a, lbase + 6, 64) + cB.z;
            z[7] = __shfl(a, lbase + 7, 64) + cB.w;
            a = ce + lse8v(z);
            Fw[(size_t)(b * NT + t) * 8 + i] = a;
        }
    } else {
        float* Bw = out + OFF_BW;
        float bv = 0.f;
        Bw[(size_t)(b * NT + NT - 1) * 8 + i] = 0.f;
        float sp[8];
        float ph, py;
        {
            const size_t t1 = (size_t)(b * NT + NT - 1);
#pragma unroll
            for (int ii = 0; ii < 8; ++ii) sp[ii] = Ps[t1 * 64 + ii * 8 + i];
            ph = Ph[t1 * 8 + i];
            py = Py[t1];
        }
        for (int t = NT - 2; t >= 0; --t) {
            float cs[8];
#pragma unroll
            for (int ii = 0; ii < 8; ++ii) cs[ii] = sp[ii];
            const float cph = ph, cpy = py;
            if (t > 0) {
                const size_t t1 = (size_t)(b * NT + t);
#pragma unroll
                for (int ii = 0; ii < 8; ++ii) sp[ii] = Ps[t1 * 64 + ii * 8 + i];
                ph = Ph[t1 * 8 + i];
                py = Py[t1];
            }
            const float v = cph + cpy + bv;
            float z[8];
#pragma unroll
            for (int j = 0; j < 8; ++j) z[j] = __shfl(v, lbase + j, 64) + cs[j];
            bv = lse8v(z);
            Bw[(size_t)(b * NT + t) * 8 + i] = bv;
        }
    }
}

__global__ void gamma1_kernel(float* __restrict__ out) {
    const int pos = blockIdx.x * 256 + threadIdx.x;  // < 16384
    const float* Fw = out + OFF_F;
    const float* Bw = out + OFF_BW;
    const float4 fa = ((const float4*)&Fw[(size_t)pos * 8])[0];
    const float4 fb = ((const float4*)&Fw[(size_t)pos * 8])[1];
    const float4 ba = ((const float4*)&Bw[(size_t)pos * 8])[0];
    const float4 bb = ((const float4*)&Bw[(size_t)pos * 8])[1];
    float ab[8] = {fa.x + ba.x, fa.y + ba.y, fa.z + ba.z, fa.w + ba.w,
                   fb.x + bb.x, fb.y + bb.y, fb.z + bb.z, fb.w + bb.w};
    const float l = lse8v(ab);
    float* G1 = out + OFF_G1;
    float4 o0 = {ab[0] - l, ab[1] - l, ab[2] - l, ab[3] - l};
    float4 o1 = {ab[4] - l, ab[5] - l, ab[6] - l, ab[7] - l};
    ((float4*)&G1[(size_t)pos * 8])[0] = o0;
    ((float4*)&G1[(size_t)pos * 8])[1] = o1;
}

__global__ void gamma2_kernel(float* __restrict__ out) {
    const int gidx = blockIdx.x * 256 + threadIdx.x;  // < 130816 = 32*511*8
    const int pos = gidx >> 3;                        // b*511 + t
    const int i = gidx & 7;
    const int b = pos / 511, t = pos - b * 511;
    const float* Ps = out + OFF_S;
    const float* Ph = out + OFF_H;
    const float* Py = out + OFF_Y;
    const float* Fw = out + OFF_F;
    const float* Bw = out + OFF_BW;
    const size_t t1 = (size_t)(b * NT + t + 1);
    const float ei = Ph[t1 * 8 + i] + Py[t1] + Bw[t1 * 8 + i];
    const float4 sa = ((const float4*)&Ps[(t1 * 8 + i) * 8])[0];
    const float4 sb = ((const float4*)&Ps[(t1 * 8 + i) * 8])[1];
    const float4 fa = ((const float4*)&Fw[(size_t)(b * NT + t) * 8])[0];
    const float4 fb = ((const float4*)&Fw[(size_t)(b * NT + t) * 8])[1];
    float z[8] = {fa.x + sa.x + ei, fa.y + sa.y + ei, fa.z + sa.z + ei, fa.w + sa.w + ei,
                  fb.x + sb.x + ei, fb.y + sb.y + ei, fb.z + sb.z + ei, fb.w + sb.w + ei};
    float M = fmaxf(fmaxf(fmaxf(z[0], z[1]), fmaxf(z[2], z[3])),
                    fmaxf(fmaxf(z[4], z[5]), fmaxf(z[6], z[7])));
    M = fmaxf(M, __shfl_xor(M, 1, 64));
    M = fmaxf(M, __shfl_xor(M, 2, 64));
    M = fmaxf(M, __shfl_xor(M, 4, 64));
    float s = 0.f;
#pragma unroll
    for (int j = 0; j < 8; ++j) s += fexp2((z[j] - M) * LOG2E);
    s += __shfl_xor(s, 1, 64);
    s += __shfl_xor(s, 2, 64);
    s += __shfl_xor(s, 4, 64);
    const float l = M + LN2 * flog2(s);
    float* G2 = out + OFF_G2;
    float4 o0 = {z[0] - l, z[1] - l, z[2] - l, z[3] - l};
    float4 o1 = {z[4] - l, z[5] - l, z[6] - l, z[7] - l};
    ((float4*)&G2[(size_t)gidx * 8])[0] = o0;
    ((float4*)&G2[(size_t)gidx * 8])[1] = o1;
}

extern "C" void kernel_launch(void* const* d_in, const int* in_sizes, int n_in, void* d_out,
                              int out_size, void* d_ws, size_t ws_size, hipStream_t stream) {
    const float* x = (const float*)d_in[0];
    const float* y = (const float*)d_in[1];
    const float* h = (const float*)d_in[2];
    const float* initials = (const float*)d_in[3];
    const float* Wih = (const float*)d_in[4];
    const float* Whh = (const float*)d_in[5];
    const float* bih = (const float*)d_in[6];
    const float* bhh = (const float*)d_in[7];
    const float* Wt = (const float*)d_in[8];
    const float* btv = (const float*)d_in[9];
    const float* W1 = (const float*)d_in[10];
    const float* b1 = (const float*)d_in[11];
    const float* W2 = (const float*)d_in[12];
    const float* b2 = (const float*)d_in[13];
    const float* W3 = (const float*)d_in[14];
    const float* b3 = (const float*)d_in[15];
    float* out = (float*)d_out;
    char* ws = (char*)d_ws;
    if (ws_size < (size_t)WS_NEED) return;
    f16* Aws = (f16*)(ws + WS_A);
    f16* Bws = (f16*)(ws + WS_B);
    float* biasc = (float*)(ws + WS_BIAS);
    float* sqp = (float*)(ws + WS_SQ);

    conv_a_kernel<<<6144, 256, 0, stream>>>(x, h, Aws);
    conv_b_kernel<<<1536, 256, 0, stream>>>(Wih, Whh, bih, bhh, Bws, biasc);
    gemm_kernel<<<4096, 256, 0, stream>>>(Aws, Bws, biasc, h, sqp);
    finalize_h_kernel<<<512, 256, 0, stream>>>(sqp, out + OFF_H);
    trans_kernel<<<511, 256, 0, stream>>>(h, Wt, btv, out + OFF_S);
    s0_kernel<<<8, 256, 0, stream>>>(out);
    emission_kernel<<<1024, 256, 0, stream>>>(h, y, W1, b1, W2, b2, W3, b3, out + OFF_Y);
    pinit_kernel<<<1, 256, 0, stream>>>(initials, out);
    scan_kernel<<<2, 256, 0, stream>>>(initials, out);
    gamma1_kernel<<<64, 256, 0, stream>>>(out);
    gamma2_kernel<<<511, 256, 0, stream>>>(out);
}

// Round 6
// 539.752 us; speedup vs baseline: 1.2140x; 1.2140x over previous
//
#include <hip/hip_runtime.h>

typedef _Float16 f16;
typedef _Float16 f16x8 __attribute__((ext_vector_type(8)));
typedef float f32x4 __attribute__((ext_vector_type(4)));
typedef float f32x16 __attribute__((ext_vector_type(16)));

#define NB 32
#define NT 512
#define ND 256
#define NH 512
#define NK 8
#define M_REAL 16352   // NB*(NT-1)
#define M_PAD 16384
#define RDIM 768       // ND + NH
#define TILE_ELEMS 98304  // 96 ch * 128 rows * 8 f16 per tile

// output offsets (floats)
#define OFF_PI 0
#define OFF_S  256
#define OFF_H  1048832
#define OFF_Y  1179904
#define OFF_G1 1196288
#define OFF_G2 1327360
#define OFF_F  2373888
#define OFF_BW 2504960

// ws offsets (bytes)
#define WS_A    0            // f16 tiled [128][96][128][8] = 25165824 B ; reused as PsT (4 MB) after gemm
#define WS_B    25165824     // f16 tiled [32][96][128][8]  = 6291456 B
#define WS_BIAS 31457280     // f32 [4096]
#define WS_SQ   31473664     // f32 [16384][8][8] = 4194304 B
#define WS_NEED 35667968

#define CH_CONST 1887.3506062251f   // -0.5*512*(log(2pi)+log(1e-4))
#define CY_CONST 943.6753031126f    // -0.5*256*(...)
#define LOG2E 1.4426950408889634f
#define LN2 0.6931471805599453f

__device__ __forceinline__ float fexp2(float x) { return __builtin_amdgcn_exp2f(x); }
__device__ __forceinline__ float flog2(float x) { return __builtin_amdgcn_logf(x); }
__device__ __forceinline__ float ftanh(float x) {
    x = fminf(10.f, fmaxf(-10.f, x));
    float t = fexp2(x * 2.885390081777927f);  // 2*log2(e)
    return (t - 1.f) * __builtin_amdgcn_rcpf(t + 1.f);
}
__device__ __forceinline__ float lse8v(const float* z) {
    float M = fmaxf(fmaxf(fmaxf(z[0], z[1]), fmaxf(z[2], z[3])),
                    fmaxf(fmaxf(z[4], z[5]), fmaxf(z[6], z[7])));
    float s = 0.f;
#pragma unroll
    for (int j = 0; j < 8; ++j) s += fexp2((z[j] - M) * LOG2E);
    return M + LN2 * flog2(s);
}

// ---------------- conversion kernels (write GEMM-tiled layout) ----------------
// tiled index for (row m, col c): (m>>7)*98304 + (c>>3)*1024 + (m&127)*8 + (c&7)
__global__ void conv_a_kernel(const float* __restrict__ x, const float* __restrict__ h,
                              f16* __restrict__ A) {
    const int g = blockIdx.x * 256 + threadIdx.x;  // < 16384*96
    const int m = g / 96;
    const int ch = g - m * 96;
    f16x8 pk = (f16x8)(f16)0.f;
    if (m < M_REAL) {
        const int b = m / 511;
        const int t = m - b * 511;
        const int c0 = ch * 8;
        const float* src = (c0 < ND) ? x + (size_t)(b * NT + t + 1) * ND + c0
                                     : h + (size_t)(b * NT + t) * NH + (c0 - ND);
        const float4 u = ((const float4*)src)[0];
        const float4 v = ((const float4*)src)[1];
        pk[0] = (f16)u.x; pk[1] = (f16)u.y; pk[2] = (f16)u.z; pk[3] = (f16)u.w;
        pk[4] = (f16)v.x; pk[5] = (f16)v.y; pk[6] = (f16)v.z; pk[7] = (f16)v.w;
    }
    const size_t dst = (size_t)(m >> 7) * TILE_ELEMS + (size_t)ch * 1024 + (size_t)(m & 127) * 8;
    *(f16x8*)(A + dst) = pk;
}

__global__ void conv_b_kernel(const float* __restrict__ Wih, const float* __restrict__ Whh,
                              const float* __restrict__ bih, const float* __restrict__ bhh,
                              f16* __restrict__ Bm, float* __restrict__ biasc) {
    const int g = blockIdx.x * 256 + threadIdx.x;  // < 4096*96
    const int n = g / 96;
    const int ch = g - n * 96;
    const int c0 = ch * 8;
    const float* src = (c0 < ND) ? Wih + (size_t)n * ND + c0 : Whh + (size_t)n * NH + (c0 - ND);
    const float4 u = ((const float4*)src)[0];
    const float4 v = ((const float4*)src)[1];
    f16x8 pk;
    pk[0] = (f16)u.x; pk[1] = (f16)u.y; pk[2] = (f16)u.z; pk[3] = (f16)u.w;
    pk[4] = (f16)v.x; pk[5] = (f16)v.y; pk[6] = (f16)v.z; pk[7] = (f16)v.w;
    const size_t dst = (size_t)(n >> 7) * TILE_ELEMS + (size_t)ch * 1024 + (size_t)(n & 127) * 8;
    *(f16x8*)(Bm + dst) = pk;
    if (ch == 0) biasc[n] = bih[n] + bhh[n];
}

// ------- big GEMM (32x32x16 MFMA, single-buffer: R4 shape) + tanh + sq epilogue
// dbuf regressed (R5): 64KB LDS dropped occupancy 3->2 blocks/CU; inter-block
// overlap at 3 blocks/CU beats intra-block prefetch at 2 (matches m99/m132).
__global__ __launch_bounds__(256) void gemm_kernel(const f16* __restrict__ A,
                                                   const f16* __restrict__ Bm,
                                                   const float* __restrict__ biasc,
                                                   const float* __restrict__ sampled_h,
                                                   float* __restrict__ sq_part) {
    __shared__ __align__(16) f16 Ash[8 * 128 * 8];
    __shared__ __align__(16) f16 Bsh[8 * 128 * 8];
    const int tid = threadIdx.x;
    const int lane = tid & 63;
    const int wave = tid >> 6;
    const int wx = wave & 1, wy = wave >> 1;
    const int xcd = blockIdx.x & 7;
    const int slot = blockIdx.x >> 3;
    const int tm = xcd * 16 + (slot >> 5);
    const int tn = slot & 31;
    const int m0 = tm * 128, n0 = tn * 128;
    const int l31 = lane & 31, hk = lane >> 5;

    f32x16 acc[2][2];
#pragma unroll
    for (int a = 0; a < 2; ++a)
#pragma unroll
        for (int b = 0; b < 2; ++b) acc[a][b] = (f32x16)0.f;

    for (int kk = 0; kk < RDIM; kk += 64) {
        __syncthreads();
        const size_t abase = (size_t)tm * TILE_ELEMS + (size_t)kk * 128;
        const size_t bbase = (size_t)tn * TILE_ELEMS + (size_t)kk * 128;
#pragma unroll
        for (int inst = 0; inst < 4; ++inst) {
            const int fb = inst * 256 + wave * 64;  // wave-uniform
            const f16* ga = A + abase + (size_t)(fb + lane) * 8;  // contiguous 1KB/inst
            const f16* gb = Bm + bbase + (size_t)(fb + lane) * 8;
            __builtin_amdgcn_global_load_lds(
                (const __attribute__((address_space(1))) void*)ga,
                (__attribute__((address_space(3))) void*)&Ash[fb * 8], 16, 0, 0);
            __builtin_amdgcn_global_load_lds(
                (const __attribute__((address_space(1))) void*)gb,
                (__attribute__((address_space(3))) void*)&Bsh[fb * 8], 16, 0, 0);
        }
        __syncthreads();
#pragma unroll
        for (int kc = 0; kc < 4; ++kc) {
            const int ch = kc * 2 + hk;
            f16x8 af[2], bfr[2];
#pragma unroll
            for (int mi = 0; mi < 2; ++mi)
                af[mi] = *(const f16x8*)&Ash[(ch * 128 + wy * 64 + mi * 32 + l31) * 8];
#pragma unroll
            for (int ni = 0; ni < 2; ++ni)
                bfr[ni] = *(const f16x8*)&Bsh[(ch * 128 + wx * 64 + ni * 32 + l31) * 8];
#pragma unroll
            for (int mi = 0; mi < 2; ++mi)
#pragma unroll
                for (int ni = 0; ni < 2; ++ni)
                    acc[mi][ni] = __builtin_amdgcn_mfma_f32_32x32x16_f16(af[mi], bfr[ni],
                                                                         acc[mi][ni], 0, 0, 0);
        }
    }

    // epilogue: C layout col=lane&31, row=(reg&3)+8*(reg>>2)+4*(lane>>5)
    const int nbase = n0 + wx * 64;
    const int k0 = n0 >> 9;
    const int slot2 = (nbase & 511) >> 6;
    const float bias0 = biasc[nbase + l31];
    const float bias1 = biasc[nbase + 32 + l31];
#pragma unroll
    for (int mi = 0; mi < 2; ++mi) {
#pragma unroll
        for (int r = 0; r < 16; ++r) {
            const int mg = m0 + wy * 64 + mi * 32 + (r & 3) + 8 * (r >> 2) + 4 * hk;
            if (mg < M_REAL) {
                const int bb = mg / 511;
                const int tt = mg - bb * 511;
                const float* tgt = sampled_h + (size_t)((bb << 9) + tt + 1) * NH;
                float rs;
                {
                    const float v0 = ftanh(acc[mi][0][r] + bias0);
                    const float d0 = tgt[(nbase + l31) & 511] - v0;
                    const float v1 = ftanh(acc[mi][1][r] + bias1);
                    const float d1 = tgt[(nbase + 32 + l31) & 511] - v1;
                    rs = d0 * d0 + d1 * d1;
                }
                rs += __shfl_xor(rs, 1, 64);
                rs += __shfl_xor(rs, 2, 64);
                rs += __shfl_xor(rs, 4, 64);
                rs += __shfl_xor(rs, 8, 64);
                rs += __shfl_xor(rs, 16, 64);
                if (l31 == 0) sq_part[(size_t)(mg * 8 + k0) * 8 + slot2] = rs;
            }
        }
    }
}

// ---------------- fused finalize_h + s0 + pinit ----------------
__global__ void misc_kernel(const float* __restrict__ sq_part,
                            const float* __restrict__ initials, float* __restrict__ out) {
    const int g = blockIdx.x * 256 + threadIdx.x;  // < 131072 = B*T*K
    const int b = g >> 12;
    const int t = (g >> 3) & 511;
    const int k = g & 7;
    float val;
    if (t == 0) {
        val = CH_CONST;
    } else {
        const int m = b * 511 + (t - 1);
        const float4* p = (const float4*)&sq_part[(size_t)(m * 8 + k) * 8];
        const float4 a = p[0], c = p[1];
        const float s = a.x + a.y + a.z + a.w + c.x + c.y + c.z + c.w;
        val = CH_CONST - 5000.f * s;  // 0.5/VAR = 5000
    }
    out[OFF_H + g] = val;
    if (g < 2048) {  // s0: identity at t=0
        const int sb = g >> 6, c = g & 63;
        out[OFF_S + (size_t)sb * NT * 64 + c] = ((c >> 3) == (c & 7)) ? 1.f : 0.f;
    }
    if (g < 256) {  // prob_initial
        float z[8];
#pragma unroll
        for (int j = 0; j < 8; ++j) z[j] = initials[j];
        out[OFF_PI + g] = z[g & 7] - lse8v(z);
    }
}

// ------ trans = tanh(h_prev @ Wt^T + bt), column log-softmax; writes Ps + PsT --
__global__ __launch_bounds__(256) void trans_kernel(const float* __restrict__ h,
                                                    const float* __restrict__ Wt,
                                                    const float* __restrict__ btv,
                                                    float* __restrict__ Ps,
                                                    float* __restrict__ PsT) {
    __shared__ float hsh[32][512];
    const int lane = threadIdx.x & 63;
    const int wave = threadIdx.x >> 6;
    const int mbase = blockIdx.x * 32 + wave * 8;  // 511 blocks * 32 rows = 16352
#pragma unroll
    for (int r = 0; r < 8; ++r) {
        const int m = mbase + r;
        const int b = m / 511, t = m - b * 511;
        const float4* src = (const float4*)(h + (size_t)(b * NT + t) * NH);
        ((float4*)hsh[wave * 8 + r])[lane] = src[lane];
        ((float4*)hsh[wave * 8 + r])[lane + 64] = src[lane + 64];
    }
    __syncthreads();
    const int c = lane;  // output index = i*8 + j
    float acc[8];
#pragma unroll
    for (int r = 0; r < 8; ++r) acc[r] = btv[c];
    const float4* w4 = (const float4*)(Wt + (size_t)c * NH);
    for (int hh = 0; hh < 128; ++hh) {
        const float4 w = w4[hh];
#pragma unroll
        for (int r = 0; r < 8; ++r) {
            const float4 hv = ((const float4*)hsh[wave * 8 + r])[hh];
            acc[r] += w.x * hv.x + w.y * hv.y + w.z * hv.z + w.w * hv.w;
        }
    }
#pragma unroll
    for (int r = 0; r < 8; ++r) {
        const float tr = ftanh(acc[r]);
        float M = tr;
        M = fmaxf(M, __shfl_xor(M, 8, 64));
        M = fmaxf(M, __shfl_xor(M, 16, 64));
        M = fmaxf(M, __shfl_xor(M, 32, 64));
        float s = fexp2((tr - M) * LOG2E);
        s += __shfl_xor(s, 8, 64);
        s += __shfl_xor(s, 16, 64);
        s += __shfl_xor(s, 32, 64);
        const float lse = M + LN2 * flog2(s);
        const int m = mbase + r;
        const int b = m / 511, t = m - b * 511;
        const float v = tr - lse;
        Ps[(size_t)(b * NT + t + 1) * 64 + c] = v;
        PsT[(size_t)(b * NT + t + 1) * 64 + (c & 7) * 8 + (c >> 3)] = v;
    }
}

// ---------------- emission MLP + gaussian lp: phase-split ----------------
__global__ __launch_bounds__(256) void emission_kernel(
    const float* __restrict__ h, const float* __restrict__ y, const float* __restrict__ W1,
    const float* __restrict__ b1, const float* __restrict__ W2, const float* __restrict__ b2,
    const float* __restrict__ W3, const float* __restrict__ b3, float* __restrict__ Py) {
    __shared__ float ssh[16][512];
    __shared__ float W2sh[64 * 33];
    __shared__ float h1sh[16][32];
    __shared__ float h2sh[16][64];
    __shared__ float red[16][4];
    const int tid = threadIdx.x;
    const int wv = tid >> 6;
    const int o = tid >> 3, seg = tid & 7;
    const int p0 = blockIdx.x * 16;
    float4 w1r[16], w3r[16];
    {
        const float4* w1p = (const float4*)(W1 + (size_t)o * NH + seg * 64);
#pragma unroll
        for (int j = 0; j < 16; ++j) w1r[j] = w1p[(j + seg * 2) & 15];  // staggered load
        const float4* w3p = (const float4*)(W3 + (size_t)tid * 64);
#pragma unroll
        for (int j = 0; j < 16; ++j) w3r[j] = w3p[j];
    }
    if (tid < 64) {
        for (int j = 0; j < 32; ++j) W2sh[tid * 33 + j] = W2[tid * 32 + j];
    }
    float yv[16];
#pragma unroll
    for (int pp = 0; pp < 16; ++pp) yv[pp] = y[(size_t)(p0 + pp) * ND + tid];
    const float b1r = b1[o];
    const float b2r = b2[tid & 63];
    const float b3r = b3[tid];
#pragma unroll
    for (int pp = 0; pp < 16; ++pp) {
        const float2 hv = ((const float2*)(h + (size_t)(p0 + pp) * NH))[tid];
        ssh[pp][tid * 2] = hv.x;
        ssh[pp][tid * 2 + 1] = hv.y;
    }
    __syncthreads();
#pragma unroll
    for (int pp = 0; pp < 16; ++pp) {
        const float4* s4 = (const float4*)&ssh[pp][seg * 64];
        float p = 0.f;
#pragma unroll
        for (int it = 0; it < 16; ++it) {
            const float4 sv = s4[(it + seg * 2) & 15];
            const float4 w = w1r[it];
            p += w.x * sv.x + w.y * sv.y + w.z * sv.z + w.w * sv.w;
        }
        p += __shfl_xor(p, 1, 64);
        p += __shfl_xor(p, 2, 64);
        p += __shfl_xor(p, 4, 64);
        if (seg == 0) h1sh[pp][o] = fmaxf(p + b1r, 0.f);
    }
    __syncthreads();
    {
        const int o2 = tid & 63;
#pragma unroll
        for (int it = 0; it < 4; ++it) {
            const int pp = wv * 4 + it;
            float s = b2r;
#pragma unroll
            for (int j = 0; j < 32; ++j) s += W2sh[o2 * 33 + j] * h1sh[pp][j];
            h2sh[pp][o2] = fmaxf(s, 0.f);
        }
    }
    __syncthreads();
#pragma unroll
    for (int pp = 0; pp < 16; ++pp) {
        float s = b3r;
        const float4* h24 = (const float4*)h2sh[pp];
#pragma unroll
        for (int j = 0; j < 16; ++j) {
            const float4 w = w3r[j], hb = h24[j];
            s += w.x * hb.x + w.y * hb.y + w.z * hb.z + w.w * hb.w;
        }
        const float d = yv[pp] - s;
        float sq = d * d;
#pragma unroll
        for (int off = 32; off > 0; off >>= 1) sq += __shfl_xor(sq, off, 64);
        if ((tid & 63) == 0) red[pp][wv] = sq;
    }
    __syncthreads();
    if (tid < 16) {
        Py[p0 + tid] = CY_CONST - 5000.f * (red[tid][0] + red[tid][1] + red[tid][2] + red[tid][3]);
    }
}

// ------- forward / backward scans: shfl-only + depth-8 register pipeline -------
// 1-step prefetch (~100 cyc) couldn't cover ~600-900 cyc load latency at a
// 2-block grid; chunked depth-8 double-buffered prefetch (~32 loads in flight,
// ~800 cyc of compute per chunk) hides it. Backward reads PsT (column-major S,
// written by trans into the dead A-staging ws region) so all loads are float4.
__global__ __launch_bounds__(256) void scan_kernel(const float* __restrict__ initials,
                                                   const float* __restrict__ PsT,
                                                   float* __restrict__ out) {
    const float* Ps = out + OFF_S;
    const float* Ph = out + OFF_H;
    const float* Py = out + OFF_Y;
    const int lane = threadIdx.x & 63;
    const int wave = threadIdx.x >> 6;
    const int b = wave * 8 + (lane >> 3);
    const int i = lane & 7;
    const int lbase = lane & ~7;

    if (blockIdx.x == 0) {
        float z0[8];
#pragma unroll
        for (int j = 0; j < 8; ++j) z0[j] = initials[j];
        float* Fw = out + OFF_F;
        float a = (z0[i] - lse8v(z0)) + CH_CONST + Py[b * NT];
        Fw[(size_t)(b * NT) * 8 + i] = a;
        float4 cA[8], cB[8]; float cH[8], cY[8];
        float4 nA[8], nB[8]; float nH[8], nY[8];
#define FLOAD(CC, A_, B_, H_, Y_)                                                  \
        _Pragma("unroll") for (int j = 0; j < 8; ++j) {                            \
            int t = 1 + (CC) * 8 + j;                                              \
            t = t > 511 ? 511 : t;                                                 \
            const size_t p = (size_t)(b * NT + t) * 64 + i * 8;                    \
            A_[j] = *(const float4*)&Ps[p];                                        \
            B_[j] = *(const float4*)&Ps[p + 4];                                    \
            H_[j] = Ph[(size_t)(b * NT + t) * 8 + i];                              \
            Y_[j] = Py[b * NT + t];                                                \
        }
#define FSTEP(CC, A_, B_, H_, Y_)                                                  \
        _Pragma("unroll") for (int j = 0; j < 8; ++j) {                            \
            const int t = 1 + (CC) * 8 + j;                                        \
            if (t < NT) {                                                          \
                float z[8];                                                        \
                z[0] = __shfl(a, lbase + 0, 64) + A_[j].x;                         \
                z[1] = __shfl(a, lbase + 1, 64) + A_[j].y;                         \
                z[2] = __shfl(a, lbase + 2, 64) + A_[j].z;                         \
                z[3] = __shfl(a, lbase + 3, 64) + A_[j].w;                         \
                z[4] = __shfl(a, lbase + 4, 64) + B_[j].x;                         \
                z[5] = __shfl(a, lbase + 5, 64) + B_[j].y;                         \
                z[6] = __shfl(a, lbase + 6, 64) + B_[j].z;                         \
                z[7] = __shfl(a, lbase + 7, 64) + B_[j].w;                         \
                a = (H_[j] + Y_[j]) + lse8v(z);                                    \
                Fw[(size_t)(b * NT + t) * 8 + i] = a;                              \
            }                                                                      \
        }
        FLOAD(0, cA, cB, cH, cY);
        for (int c = 0; c < 64; c += 2) {
            const int c1 = c + 1;
            const int c2 = (c + 2 < 64) ? c + 2 : 63;
            FLOAD(c1, nA, nB, nH, nY);
            FSTEP(c, cA, cB, cH, cY);
            FLOAD(c2, cA, cB, cH, cY);
            FSTEP(c1, nA, nB, nH, nY);
        }
#undef FLOAD
#undef FSTEP
    } else {
        float* Bw = out + OFF_BW;
        float bv = 0.f;
        Bw[(size_t)(b * NT + NT - 1) * 8 + i] = 0.f;
        float4 cA[8], cB[8]; float cH[8], cY[8];
        float4 nA[8], nB[8]; float nH[8], nY[8];
#define BLOAD(CC, A_, B_, H_, Y_)                                                  \
        _Pragma("unroll") for (int j = 0; j < 8; ++j) {                            \
            int t = 510 - ((CC) * 8 + j);                                          \
            t = t < 0 ? 0 : t;                                                     \
            const size_t t1 = (size_t)(b * NT + t + 1);                            \
            const size_t p = t1 * 64 + i * 8;                                      \
            A_[j] = *(const float4*)&PsT[p];                                       \
            B_[j] = *(const float4*)&PsT[p + 4];                                   \
            H_[j] = Ph[t1 * 8 + i];                                                \
            Y_[j] = Py[t1];                                                        \
        }
#define BSTEP(CC, A_, B_, H_, Y_)                                                  \
        _Pragma("unroll") for (int j = 0; j < 8; ++j) {                            \
            const int t = 510 - ((CC) * 8 + j);                                    \
            if (t >= 0) {                                                          \
                const float v = H_[j] + Y_[j] + bv;                                \
                float z[8];                                                        \
                z[0] = __shfl(v, lbase + 0, 64) + A_[j].x;                         \
                z[1] = __shfl(v, lbase + 1, 64) + A_[j].y;                         \
                z[2] = __shfl(v, lbase + 2, 64) + A_[j].z;                         \
                z[3] = __shfl(v, lbase + 3, 64) + A_[j].w;                         \
                z[4] = __shfl(v, lbase + 4, 64) + B_[j].x;                         \
                z[5] = __shfl(v, lbase + 5, 64) + B_[j].y;                         \
                z[6] = __shfl(v, lbase + 6, 64) + B_[j].z;                         \
                z[7] = __shfl(v, lbase + 7, 64) + B_[j].w;                         \
                bv = lse8v(z);                                                     \
                Bw[(size_t)(b * NT + t) * 8 + i] = bv;                             \
            }                                                                      \
        }
        BLOAD(0, cA, cB, cH, cY);
        for (int c = 0; c < 64; c += 2) {
            const int c1 = c + 1;
            const int c2 = (c + 2 < 64) ? c + 2 : 63;
            BLOAD(c1, nA, nB, nH, nY);
            BSTEP(c, cA, cB, cH, cY);
            BLOAD(c2, cA, cB, cH, cY);
            BSTEP(c1, nA, nB, nH, nY);
        }
#undef BLOAD
#undef BSTEP
    }
}

__global__ void gamma1_kernel(float* __restrict__ out) {
    const int pos = blockIdx.x * 256 + threadIdx.x;  // < 16384
    const float* Fw = out + OFF_F;
    const float* Bw = out + OFF_BW;
    const float4 fa = ((const float4*)&Fw[(size_t)pos * 8])[0];
    const float4 fb = ((const float4*)&Fw[(size_t)pos * 8])[1];
    const float4 ba = ((const float4*)&Bw[(size_t)pos * 8])[0];
    const float4 bb = ((const float4*)&Bw[(size_t)pos * 8])[1];
    float ab[8] = {fa.x + ba.x, fa.y + ba.y, fa.z + ba.z, fa.w + ba.w,
                   fb.x + bb.x, fb.y + bb.y, fb.z + bb.z, fb.w + bb.w};
    const float l = lse8v(ab);
    float* G1 = out + OFF_G1;
    float4 o0 = {ab[0] - l, ab[1] - l, ab[2] - l, ab[3] - l};
    float4 o1 = {ab[4] - l, ab[5] - l, ab[6] - l, ab[7] - l};
    ((float4*)&G1[(size_t)pos * 8])[0] = o0;
    ((float4*)&G1[(size_t)pos * 8])[1] = o1;
}

__global__ void gamma2_kernel(float* __restrict__ out) {
    const int gidx = blockIdx.x * 256 + threadIdx.x;  // < 130816 = 32*511*8
    const int pos = gidx >> 3;                        // b*511 + t
    const int i = gidx & 7;
    const int b = pos / 511, t = pos - b * 511;
    const float* Ps = out + OFF_S;
    const float* Ph = out + OFF_H;
    const float* Py = out + OFF_Y;
    const float* Fw = out + OFF_F;
    const float* Bw = out + OFF_BW;
    const size_t t1 = (size_t)(b * NT + t + 1);
    const float ei = Ph[t1 * 8 + i] + Py[t1] + Bw[t1 * 8 + i];
    const float4 sa = ((const float4*)&Ps[(t1 * 8 + i) * 8])[0];
    const float4 sb = ((const float4*)&Ps[(t1 * 8 + i) * 8])[1];
    const float4 fa = ((const float4*)&Fw[(size_t)(b * NT + t) * 8])[0];
    const float4 fb = ((const float4*)&Fw[(size_t)(b * NT + t) * 8])[1];
    float z[8] = {fa.x + sa.x + ei, fa.y + sa.y + ei, fa.z + sa.z + ei, fa.w + sa.w + ei,
                  fb.x + sb.x + ei, fb.y + sb.y + ei, fb.z + sb.z + ei, fb.w + sb.w + ei};
    float M = fmaxf(fmaxf(fmaxf(z[0], z[1]), fmaxf(z[2], z[3])),
                    fmaxf(fmaxf(z[4], z[5]), fmaxf(z[6], z[7])));
    M = fmaxf(M, __shfl_xor(M, 1, 64));
    M = fmaxf(M, __shfl_xor(M, 2, 64));
    M = fmaxf(M, __shfl_xor(M, 4, 64));
    float s = 0.f;
#pragma unroll
    for (int j = 0; j < 8; ++j) s += fexp2((z[j] - M) * LOG2E);
    s += __shfl_xor(s, 1, 64);
    s += __shfl_xor(s, 2, 64);
    s += __shfl_xor(s, 4, 64);
    const float l = M + LN2 * flog2(s);
    float* G2 = out + OFF_G2;
    float4 o0 = {z[0] - l, z[1] - l, z[2] - l, z[3] - l};
    float4 o1 = {z[4] - l, z[5] - l, z[6] - l, z[7] - l};
    ((float4*)&G2[(size_t)gidx * 8])[0] = o0;
    ((float4*)&G2[(size_t)gidx * 8])[1] = o1;
}

extern "C" void kernel_launch(void* const* d_in, const int* in_sizes, int n_in, void* d_out,
                              int out_size, void* d_ws, size_t ws_size, hipStream_t stream) {
    const float* x = (const float*)d_in[0];
    const float* y = (const float*)d_in[1];
    const float* h = (const float*)d_in[2];
    const float* initials = (const float*)d_in[3];
    const float* Wih = (const float*)d_in[4];
    const float* Whh = (const float*)d_in[5];
    const float* bih = (const float*)d_in[6];
    const float* bhh = (const float*)d_in[7];
    const float* Wt = (const float*)d_in[8];
    const float* btv = (const float*)d_in[9];
    const float* W1 = (const float*)d_in[10];
    const float* b1 = (const float*)d_in[11];
    const float* W2 = (const float*)d_in[12];
    const float* b2 = (const float*)d_in[13];
    const float* W3 = (const float*)d_in[14];
    const float* b3 = (const float*)d_in[15];
    float* out = (float*)d_out;
    char* ws = (char*)d_ws;
    if (ws_size < (size_t)WS_NEED) return;
    f16* Aws = (f16*)(ws + WS_A);
    f16* Bws = (f16*)(ws + WS_B);
    float* biasc = (float*)(ws + WS_BIAS);
    float* sqp = (float*)(ws + WS_SQ);
    float* PsT = (float*)(ws + WS_A);  // reuses A staging (dead after gemm)

    conv_a_kernel<<<6144, 256, 0, stream>>>(x, h, Aws);
    conv_b_kernel<<<1536, 256, 0, stream>>>(Wih, Whh, bih, bhh, Bws, biasc);
    gemm_kernel<<<4096, 256, 0, stream>>>(Aws, Bws, biasc, h, sqp);
    misc_kernel<<<512, 256, 0, stream>>>(sqp, initials, out);
    trans_kernel<<<511, 256, 0, stream>>>(h, Wt, btv, out + OFF_S, PsT);
    emission_kernel<<<1024, 256, 0, stream>>>(h, y, W1, b1, W2, b2, W3, b3, out + OFF_Y);
    scan_kernel<<<2, 256, 0, stream>>>(initials, PsT, out);
    gamma1_kernel<<<64, 256, 0, stream>>>(out);
    gamma2_kernel<<<511, 256, 0, stream>>>(out);
}